// Round 2
// baseline (2155.920 us; speedup 1.0000x reference)
//
#include <hip/hip_runtime.h>
#include <math.h>
#include <stdint.h>

#define DDIM 256
#define CAP  320
#define NCLS 50

// global -> LDS direct copy, 16B per lane. LDS dest must be wave-uniform;
// HW writes to dest + lane*16. Global source is per-lane.
__device__ __forceinline__ void gl_lds16(const void* g, void* l) {
  __builtin_amdgcn_global_load_lds(
      (__attribute__((address_space(1))) unsigned int*)(uintptr_t)g,
      (__attribute__((address_space(3))) unsigned int*)l,
      16, 0, 0);
}

// ---------------------------------------------------------------- col sumsq
// colsq[d] = sum_n train[n][d]^2  (double accum)
__global__ void k_colsq(const float* __restrict__ train, double* __restrict__ colsq,
                        int N) {
  const int t = threadIdx.x;            // dim, 256 threads
  const int nb = gridDim.x;
  const int per = (N + nb - 1) / nb;
  const int r0 = blockIdx.x * per;
  const int r1 = (r0 + per < N) ? (r0 + per) : N;
  double acc = 0.0;
  for (int r = r0; r < r1; ++r) {
    float v = train[(size_t)r * DDIM + t];
    acc = fma((double)v, (double)v, acc);
  }
  atomicAdd(&colsq[t], acc);
}

// ---------------------------------------------------------------- prep query
// qs[b][d] = (test[b][d]/max(||test[b]||,eps)) / max(colnorm[d],eps)
// tau[b]   = 3.35 * ||qs[b]||  (sim ~ N(0,||qs||^2); E[count>tau] ~ 81)
__global__ void k_prep(const float* __restrict__ test, const double* __restrict__ colsq,
                       float* __restrict__ qs, float* __restrict__ tau, int B) {
  const int row = blockIdx.x, t = threadIdx.x;
  const int wid = t >> 6, lane = t & 63;
  __shared__ float ps[4];
  __shared__ float stot;
  float v = test[(size_t)row * DDIM + t];
  float ss = v * v;
#pragma unroll
  for (int o = 32; o > 0; o >>= 1) ss += __shfl_down(ss, o, 64);
  if (lane == 0) ps[wid] = ss;
  __syncthreads();
  if (t == 0) stot = ps[0] + ps[1] + ps[2] + ps[3];
  __syncthreads();
  float rn   = fmaxf(sqrtf(stot), 1e-12f);
  float coln = fmaxf(sqrtf((float)colsq[t]), 1e-12f);
  float qv   = (v / rn) / coln;
  qs[(size_t)row * DDIM + t] = qv;
  float s2 = qv * qv;
#pragma unroll
  for (int o = 32; o > 0; o >>= 1) s2 += __shfl_down(s2, o, 64);
  if (lane == 0) ps[wid] = s2;
  __syncthreads();
  if (t == 0) tau[row] = 3.35f * sqrtf(ps[0] + ps[1] + ps[2] + ps[3]);
}

// ---------------------------------------------------------------- main GEMM
// 128x64 tile, BK=32, 256 threads (tx 0..15, ty 0..15), 8x4 acc/thread.
// LDS frag layout: Xs4[m*ITEMS + item], m = k4 index within 32-K slice.
#define DOT4(ACC, A, Bv)                                                     \
  ACC = fmaf((A).x, (Bv).x, ACC); ACC = fmaf((A).y, (Bv).y, ACC);            \
  ACC = fmaf((A).z, (Bv).z, ACC); ACC = fmaf((A).w, (Bv).w, ACC);

__global__ __launch_bounds__(256, 4)
void k_gemm(const float* __restrict__ train, const float* __restrict__ qs,
            const float* __restrict__ tau, int* __restrict__ cidx,
            int* __restrict__ cnt, int N, int B, int tpc) {
  __shared__ float4 As4[8 * 128];   // 16 KB : A slice 128 rows x 32 k
  __shared__ float4 Bs4[8 * 64];    //  8 KB : B slice  64 cols x 32 k
  const int tid = threadIdx.x;
  const int tx = tid & 15, ty = tid >> 4;
  const int wid = tid >> 6, lane = tid & 63;
  const int row0 = blockIdx.y * 128;
  const int colbase = blockIdx.x * tpc * 64;

  float tau_r[8];
#pragma unroll
  for (int i = 0; i < 8; ++i) {
    int r = row0 + ty + 16 * i; if (r >= B) r = B - 1;
    tau_r[i] = tau[r];
  }
  int rL = row0 + lane;      if (rL >= B) rL = B - 1;
  int rH = row0 + 64 + lane; if (rH >= B) rH = B - 1;
  const float* aptrL = qs + (size_t)rL * DDIM;
  const float* aptrH = qs + (size_t)rH * DDIM;

  for (int tile = 0; tile < tpc; ++tile) {
    const int col0 = colbase + tile * 64;
    if (col0 >= N) break;
    int bcol = col0 + lane; if (bcol >= N) bcol = N - 1;
    const float* bptr = train + (size_t)bcol * DDIM;

    float acc[8][4];
#pragma unroll
    for (int i = 0; i < 8; ++i)
#pragma unroll
      for (int j = 0; j < 4; ++j) acc[i][j] = 0.f;

    for (int s = 0; s < 8; ++s) {      // 8 K-slices of 32
      const int kk0 = s * 32;
      __syncthreads();                 // prior reads done before overwrite
      // A: 16 wave-loads (slot = wid+4*j -> m = slot>>1, half = slot&1)
#pragma unroll
      for (int j = 0; j < 4; ++j) {
        const int slot = wid + 4 * j;
        const int m = slot >> 1, half = slot & 1;
        gl_lds16((half ? aptrH : aptrL) + kk0 + 4 * m, &As4[m * 128 + half * 64]);
      }
      // B: 8 wave-loads (m = wid+4*j)
#pragma unroll
      for (int j = 0; j < 2; ++j) {
        const int m = wid + 4 * j;
        gl_lds16(bptr + kk0 + 4 * m, &Bs4[m * 64]);
      }
      __syncthreads();                 // drains vmcnt(0): staged data landed
#pragma unroll
      for (int k4 = 0; k4 < 8; ++k4) {
        float4 a[8], b[4];
#pragma unroll
        for (int i = 0; i < 8; ++i) a[i] = As4[k4 * 128 + ty + 16 * i];
#pragma unroll
        for (int j = 0; j < 4; ++j) b[j] = Bs4[k4 * 64 + tx + 16 * j];
#pragma unroll
        for (int i = 0; i < 8; ++i)
#pragma unroll
          for (int j = 0; j < 4; ++j) { DOT4(acc[i][j], a[i], b[j]) }
      }
    }
    // epilogue: rare threshold-append (indices only; values rescored later)
#pragma unroll
    for (int i = 0; i < 8; ++i) {
      const int r = row0 + ty + 16 * i;
#pragma unroll
      for (int j = 0; j < 4; ++j) {
        const int c = col0 + tx + 16 * j;
        if (acc[i][j] > tau_r[i] && c < N && r < B) {
          int p = atomicAdd(&cnt[r], 1);
          if (p < CAP) cidx[(size_t)r * CAP + p] = c;
        }
      }
    }
  }
}

// ---------------------------------------------------------------- fallback
// Exact full rescan for any row with cnt<10 or cnt>CAP (statistically never).
__global__ void k_fallback(const float* __restrict__ train, const float* __restrict__ qs,
                           int* __restrict__ cidx, int* __restrict__ cnt, int N) {
  const int row = blockIdx.x;
  const int t = threadIdx.x;
  const int c0 = cnt[row];
  if (c0 >= 10 && c0 <= CAP) return;    // block-uniform
  __shared__ float q[DDIM];
  if (t < DDIM) q[t] = qs[(size_t)row * DDIM + t];
  __syncthreads();
  float lv[10]; int li[10];
#pragma unroll
  for (int k = 0; k < 10; ++k) { lv[k] = -INFINITY; li[k] = 0x7FFFFFFF; }
  for (int c = t; c < N; c += 256) {
    const float* tr = train + (size_t)c * DDIM;
    float s = 0.f;
    for (int d = 0; d < DDIM; ++d) s = fmaf(q[d], tr[d], s);
    if (s > lv[9]) {                    // strict > keeps earliest (lowest idx)
      int p = 9;
      while (p > 0 && s > lv[p - 1]) { lv[p] = lv[p - 1]; li[p] = li[p - 1]; --p; }
      lv[p] = s; li[p] = c;
    }
  }
  __shared__ float rv[256]; __shared__ int ri[256]; __shared__ int rt_[256];
  __shared__ int topi[10];
  int pt = 0;
  for (int k = 0; k < 10; ++k) {
    rv[t] = (pt < 10) ? lv[pt] : -INFINITY;
    ri[t] = (pt < 10) ? li[pt] : 0x7FFFFFFF;
    rt_[t] = t;
    __syncthreads();
    for (int s2 = 128; s2 > 0; s2 >>= 1) {
      if (t < s2) {
        float ov = rv[t + s2]; int oi = ri[t + s2];
        if (ov > rv[t] || (ov == rv[t] && oi < ri[t])) {
          rv[t] = ov; ri[t] = oi; rt_[t] = rt_[t + s2];
        }
      }
      __syncthreads();
    }
    const int win = rt_[0];
    if (t == 0) topi[k] = ri[0];
    __syncthreads();
    if (t == win) ++pt;
  }
  if (t < 10) cidx[(size_t)row * CAP + t] = topi[t];
  if (t == 0) cnt[row] = 10;
}

// ---------------------------------------------------------------- rescore
// fp64-accurate sim for every candidate: one wave per candidate, coalesced.
__global__ void k_rescore(const float* __restrict__ train, const float* __restrict__ qs,
                          const int* __restrict__ cidx, const int* __restrict__ cnt,
                          double* __restrict__ dval) {
  const int row = blockIdx.x;
  const int t = threadIdx.x, wid = t >> 6, lane = t & 63;
  __shared__ float qsh[DDIM];
  if (t < DDIM) qsh[t] = qs[(size_t)row * DDIM + t];
  __syncthreads();
  int n = cnt[row]; if (n > CAP) n = CAP;
  for (int ci = wid; ci < n; ci += 4) {
    const int c = cidx[(size_t)row * CAP + ci];
    const float4 tv = *(const float4*)(train + (size_t)c * DDIM + lane * 4);
    const float4 qv = *(const float4*)(qsh + lane * 4);
    double s = (double)tv.x * qv.x + (double)tv.y * qv.y +
               (double)tv.z * qv.z + (double)tv.w * qv.w;
#pragma unroll
    for (int o = 32; o > 0; o >>= 1) s += __shfl_down(s, o, 64);
    if (lane == 0) dval[(size_t)row * CAP + ci] = s;
  }
}

// ---------------------------------------------------------------- finalize
// exact top-10 on fp64 sims (value desc, index asc = lax.top_k tie-break),
// softmax, label scatter.
__global__ void k_finalize(const double* __restrict__ dval, const int* __restrict__ cidx,
                           const int* __restrict__ cnt, const int* __restrict__ labels,
                           float* __restrict__ out) {
  const int row = blockIdx.x;
  const int t = threadIdx.x;   // 256
  int n = cnt[row]; if (n > CAP) n = CAP;
  __shared__ double sv[CAP]; __shared__ int si[CAP];
  for (int i = t; i < CAP; i += 256) {
    sv[i] = (i < n) ? dval[(size_t)row * CAP + i] : -INFINITY;
    si[i] = (i < n) ? cidx[(size_t)row * CAP + i] : 0x7FFFFFFF;
  }
  __syncthreads();
  __shared__ double rv[256]; __shared__ int ri[256]; __shared__ int rp[256];
  __shared__ double topv[10]; __shared__ int topl[10];
  __shared__ int wpos;
  for (int k = 0; k < 10; ++k) {
    double bv = sv[t]; int bi = si[t]; int bp = t;
    if (t + 256 < CAP) {
      double v2 = sv[t + 256]; int i2 = si[t + 256];
      if (v2 > bv || (v2 == bv && i2 < bi)) { bv = v2; bi = i2; bp = t + 256; }
    }
    rv[t] = bv; ri[t] = bi; rp[t] = bp;
    __syncthreads();
    for (int s2 = 128; s2 > 0; s2 >>= 1) {
      if (t < s2) {
        double ov = rv[t + s2]; int oi = ri[t + s2];
        if (ov > rv[t] || (ov == rv[t] && oi < ri[t])) {
          rv[t] = ov; ri[t] = oi; rp[t] = rp[t + s2];
        }
      }
      __syncthreads();
    }
    if (t == 0) { topv[k] = rv[0]; topl[k] = ri[0]; wpos = rp[0]; }
    __syncthreads();
    if (t == 0) sv[wpos] = -INFINITY;   // remove winner
    __syncthreads();
  }
  __shared__ double oc[NCLS];
  if (t < NCLS) oc[t] = 0.0;
  __syncthreads();
  if (t == 0) {
    const double m = topv[0];
    double w[10]; double ssum = 0.0;
#pragma unroll
    for (int k = 0; k < 10; ++k) { w[k] = exp((topv[k] - m) / 0.07); ssum += w[k]; }
#pragma unroll
    for (int k = 0; k < 10; ++k) oc[labels[topl[k]]] += w[k] / ssum;
  }
  __syncthreads();
  if (t < NCLS) out[(size_t)row * NCLS + t] = (float)oc[t];
}

// ---------------------------------------------------------------- launch
extern "C" void kernel_launch(void* const* d_in, const int* in_sizes, int n_in,
                              void* d_out, int out_size, void* d_ws, size_t ws_size,
                              hipStream_t stream) {
  const float* test   = (const float*)d_in[0];
  const float* train  = (const float*)d_in[1];
  const int*   labels = (const int*)d_in[2];
  float* out = (float*)d_out;
  const int B = in_sizes[0] / DDIM;   // 1024
  const int N = in_sizes[2];          // 200000

  // workspace layout
  char* w = (char*)d_ws;
  double* colsq = (double*)w;                                   // 2048 B
  size_t off = 2048;
  int*    cnt  = (int*)(w + off);    off += (size_t)B * 4;
  float*  tau  = (float*)(w + off);  off += (size_t)B * 4;
  float*  qs   = (float*)(w + off);  off += (size_t)B * DDIM * 4;
  int*    cidx = (int*)(w + off);    off += (size_t)B * CAP * 4;
  double* dval = (double*)(w + off); off += (size_t)B * CAP * 8;
  (void)ws_size; (void)n_in; (void)out_size;

  hipMemsetAsync(d_ws, 0, 2048 + (size_t)B * 4, stream);        // colsq + cnt

  hipLaunchKernelGGL(k_colsq, dim3(256), dim3(256), 0, stream, train, colsq, N);
  hipLaunchKernelGGL(k_prep,  dim3(B),   dim3(256), 0, stream, test, colsq, qs, tau, B);

  const int CT = (N + 63) / 64;            // column tiles (BN=64)
  const int rb = (B + 127) / 128;          // row blocks (BM=128)
  int bx = 2048 / (rb > 0 ? rb : 1); if (bx < 1) bx = 1;
  int tpc = (CT + bx - 1) / bx;
  int chunks = (CT + tpc - 1) / tpc;
  hipLaunchKernelGGL(k_gemm, dim3(chunks, rb), dim3(256), 0, stream,
                     train, qs, tau, cidx, cnt, N, B, tpc);

  hipLaunchKernelGGL(k_fallback, dim3(B), dim3(256), 0, stream,
                     train, qs, cidx, cnt, N);
  hipLaunchKernelGGL(k_rescore,  dim3(B), dim3(256), 0, stream,
                     train, qs, cidx, cnt, dval);
  hipLaunchKernelGGL(k_finalize, dim3(B), dim3(256), 0, stream,
                     dval, cidx, cnt, labels, out);
}

// Round 5
// 619.075 us; speedup vs baseline: 3.4825x; 3.4825x over previous
//
#include <hip/hip_runtime.h>
#include <hip/hip_bf16.h>
#include <math.h>
#include <stdint.h>

#define DDIM 256
#define CAP  320
#define NCLS 50

typedef short bf16x8_t __attribute__((ext_vector_type(8)));  // 8 bf16 bits
typedef float f32x4_t  __attribute__((ext_vector_type(4)));

// global -> LDS direct copy, 16B/lane. LDS dest wave-uniform base + lane*16;
// global source per-lane. (hardware-proven in R2's fp32 k_gemm)
__device__ __forceinline__ void gl_lds16(const void* g, void* l) {
  __builtin_amdgcn_global_load_lds(
      (__attribute__((address_space(1))) unsigned int*)(uintptr_t)g,
      (__attribute__((address_space(3))) unsigned int*)l,
      16, 0, 0);
}

// ------------------------------------------------- fused cast + col sumsq
// tbf may be nullptr (fallback path: no bf16 buffer in workspace!)
__global__ void k_cast_colsq(const float* __restrict__ train,
                             __hip_bfloat16* __restrict__ tbf,
                             double* __restrict__ colsq, int N) {
  const int t = threadIdx.x;            // dim
  const int nb = gridDim.x;
  const int per = (N + nb - 1) / nb;
  const int r0 = blockIdx.x * per;
  const int r1 = (r0 + per < N) ? (r0 + per) : N;
  double acc = 0.0;
  int r = r0;
  for (; r + 4 <= r1; r += 4) {
    float v0 = train[(size_t)(r + 0) * DDIM + t];
    float v1 = train[(size_t)(r + 1) * DDIM + t];
    float v2 = train[(size_t)(r + 2) * DDIM + t];
    float v3 = train[(size_t)(r + 3) * DDIM + t];
    if (tbf) {
      tbf[(size_t)(r + 0) * DDIM + t] = __float2bfloat16(v0);
      tbf[(size_t)(r + 1) * DDIM + t] = __float2bfloat16(v1);
      tbf[(size_t)(r + 2) * DDIM + t] = __float2bfloat16(v2);
      tbf[(size_t)(r + 3) * DDIM + t] = __float2bfloat16(v3);
    }
    acc = fma((double)v0, (double)v0, acc);
    acc = fma((double)v1, (double)v1, acc);
    acc = fma((double)v2, (double)v2, acc);
    acc = fma((double)v3, (double)v3, acc);
  }
  for (; r < r1; ++r) {
    float v = train[(size_t)r * DDIM + t];
    if (tbf) tbf[(size_t)r * DDIM + t] = __float2bfloat16(v);
    acc = fma((double)v, (double)v, acc);
  }
  atomicAdd(&colsq[t], acc);
}

// ------------------------------------------------- prep query
// qs[b][d] = (test[b][d]/max(||test[b]||,eps)) / max(colnorm[d],eps)
// qs_bf = bf16(qs);  tau[b] = 3.30 * ||qs[b]||  (filter threshold)
__global__ void k_prep(const float* __restrict__ test, const double* __restrict__ colsq,
                       float* __restrict__ qs, __hip_bfloat16* __restrict__ qs_bf,
                       float* __restrict__ tau, int B) {
  const int row = blockIdx.x, t = threadIdx.x;
  const int wid = t >> 6, lane = t & 63;
  __shared__ float ps[4];
  __shared__ float stot;
  float v = test[(size_t)row * DDIM + t];
  float ss = v * v;
#pragma unroll
  for (int o = 32; o > 0; o >>= 1) ss += __shfl_down(ss, o, 64);
  if (lane == 0) ps[wid] = ss;
  __syncthreads();
  if (t == 0) stot = ps[0] + ps[1] + ps[2] + ps[3];
  __syncthreads();
  float rn   = fmaxf(sqrtf(stot), 1e-12f);
  float coln = fmaxf(sqrtf((float)colsq[t]), 1e-12f);
  float qv   = (v / rn) / coln;
  qs[(size_t)row * DDIM + t] = qv;
  qs_bf[(size_t)row * DDIM + t] = __float2bfloat16(qv);
  float s2 = qv * qv;
#pragma unroll
  for (int o = 32; o > 0; o >>= 1) s2 += __shfl_down(s2, o, 64);
  if (lane == 0) ps[wid] = s2;
  __syncthreads();
  if (t == 0) tau[row] = 3.30f * sqrtf(ps[0] + ps[1] + ps[2] + ps[3]);
}

// ------------------------------------------------- MFMA filter GEMM (bf16)
// 128x128 tile, BK=32, 4 waves 2x2, each wave 64x64 = 4x4 frags of 16x16x32.
// LDS fragment-major: group g (16 items) = 1024 B: lane l holds
// (item g*16+(l&15), k (l>>4)*8..+7). Staged per-lane-global -> linear LDS;
// frag reads are ds_read_b128 at lane*16 (canonical conflict-free pattern).
// A and B staged with the SAME (lane,reg)->k map => k-order invariant.
__global__ __launch_bounds__(256, 3)
void k_mfma(const __hip_bfloat16* __restrict__ qs_bf,
            const __hip_bfloat16* __restrict__ train_bf,
            const float* __restrict__ tau, int* __restrict__ cidx,
            int* __restrict__ cnt, int N, int B) {
  __shared__ __align__(16) char sAB[2][16384];   // [buf][A 8KB | B 8KB]
  __shared__ float tau_s[128];
  const int tid = threadIdx.x;
  const int w = tid >> 6, lane = tid & 63;
  const int wr = w >> 1, wc = w & 1;
  const int row0 = blockIdx.y * 128;
  const int col0 = blockIdx.x * 128;
  const int l15 = lane & 15, l4 = lane >> 4;

  if (tid < 128) {
    int rr = row0 + tid; if (rr >= B) rr = B - 1;
    tau_s[tid] = tau[rr];
  }

  // staging sources: wave w loads A groups {2w,2w+1} and B groups {2w,2w+1}
  const int g0 = 2 * w, g1 = 2 * w + 1;
  int ar0 = row0 + g0 * 16 + l15; if (ar0 >= B) ar0 = B - 1;
  int ar1 = row0 + g1 * 16 + l15; if (ar1 >= B) ar1 = B - 1;
  const __hip_bfloat16* aS0 = qs_bf + (size_t)ar0 * DDIM + l4 * 8;
  const __hip_bfloat16* aS1 = qs_bf + (size_t)ar1 * DDIM + l4 * 8;
  int bc0 = col0 + g0 * 16 + l15; if (bc0 >= N) bc0 = N - 1;
  int bc1 = col0 + g1 * 16 + l15; if (bc1 >= N) bc1 = N - 1;
  const __hip_bfloat16* bS0 = train_bf + (size_t)bc0 * DDIM + l4 * 8;
  const __hip_bfloat16* bS1 = train_bf + (size_t)bc1 * DDIM + l4 * 8;

  f32x4_t acc[4][4];
#pragma unroll
  for (int m = 0; m < 4; ++m)
#pragma unroll
    for (int n = 0; n < 4; ++n) acc[m][n] = (f32x4_t){0.f, 0.f, 0.f, 0.f};

  // prologue: stage k-step 0 into buf 0
  {
    char* A0 = sAB[0]; char* B0 = sAB[0] + 8192;
    gl_lds16(aS0, A0 + g0 * 1024);
    gl_lds16(aS1, A0 + g1 * 1024);
    gl_lds16(bS0, B0 + g0 * 1024);
    gl_lds16(bS1, B0 + g1 * 1024);
  }
  __syncthreads();   // compiler drains vmcnt(0) before s_barrier

  for (int s = 0; s < 8; ++s) {      // K = 8 * 32
    const int cur = s & 1;
    if (s < 7) {                     // issue next-slice loads first (overlap)
      const int ko = (s + 1) * 32;   // element offset
      char* An = sAB[cur ^ 1]; char* Bn = An + 8192;
      gl_lds16(aS0 + ko, An + g0 * 1024);
      gl_lds16(aS1 + ko, An + g1 * 1024);
      gl_lds16(bS0 + ko, Bn + g0 * 1024);
      gl_lds16(bS1 + ko, Bn + g1 * 1024);
    }
    const char* Ac = sAB[cur]; const char* Bc = Ac + 8192;
    bf16x8_t af[4], bfr[4];
#pragma unroll
    for (int m = 0; m < 4; ++m)
      af[m] = *(const bf16x8_t*)(Ac + (wr * 4 + m) * 1024 + lane * 16);
#pragma unroll
    for (int n = 0; n < 4; ++n)
      bfr[n] = *(const bf16x8_t*)(Bc + (wc * 4 + n) * 1024 + lane * 16);
#pragma unroll
    for (int m = 0; m < 4; ++m)
#pragma unroll
      for (int n = 0; n < 4; ++n)
        acc[m][n] = __builtin_amdgcn_mfma_f32_16x16x32_bf16(af[m], bfr[n],
                                                            acc[m][n], 0, 0, 0);
    __syncthreads();                 // drains vmcnt(0): next slice landed
  }

  // epilogue: threshold-append. D layout: col=lane&15, row=(lane>>4)*4+r.
#pragma unroll
  for (int m = 0; m < 4; ++m) {
#pragma unroll
    for (int n = 0; n < 4; ++n) {
      const int col = col0 + wc * 64 + n * 16 + l15;
      if (col < N) {
#pragma unroll
        for (int r = 0; r < 4; ++r) {
          const int rl = wr * 64 + m * 16 + l4 * 4 + r;
          if (acc[m][n][r] > tau_s[rl] && row0 + rl < B) {
            int p = atomicAdd(&cnt[row0 + rl], 1);
            if (p < CAP) cidx[(size_t)(row0 + rl) * CAP + p] = col;
          }
        }
      }
    }
  }
}

// ------------------------------------------------- fp32 filter (ws fallback)
#define DOT4(ACC, A, Bv)                                                     \
  ACC = fmaf((A).x, (Bv).x, ACC); ACC = fmaf((A).y, (Bv).y, ACC);            \
  ACC = fmaf((A).z, (Bv).z, ACC); ACC = fmaf((A).w, (Bv).w, ACC);

__global__ __launch_bounds__(256, 4)
void k_gemm(const float* __restrict__ train, const float* __restrict__ qs,
            const float* __restrict__ tau, int* __restrict__ cidx,
            int* __restrict__ cnt, int N, int B, int tpc) {
  __shared__ float4 As4[8 * 128];
  __shared__ float4 Bs4[8 * 64];
  const int tid = threadIdx.x;
  const int tx = tid & 15, ty = tid >> 4;
  const int wid = tid >> 6, lane = tid & 63;
  const int row0 = blockIdx.y * 128;
  const int colbase = blockIdx.x * tpc * 64;
  float tau_r[8];
#pragma unroll
  for (int i = 0; i < 8; ++i) {
    int r = row0 + ty + 16 * i; if (r >= B) r = B - 1;
    tau_r[i] = tau[r];
  }
  int rL = row0 + lane;      if (rL >= B) rL = B - 1;
  int rH = row0 + 64 + lane; if (rH >= B) rH = B - 1;
  const float* aptrL = qs + (size_t)rL * DDIM;
  const float* aptrH = qs + (size_t)rH * DDIM;
  for (int tile = 0; tile < tpc; ++tile) {
    const int col0 = colbase + tile * 64;
    if (col0 >= N) break;
    int bcol = col0 + lane; if (bcol >= N) bcol = N - 1;
    const float* bptr = train + (size_t)bcol * DDIM;
    float acc[8][4];
#pragma unroll
    for (int i = 0; i < 8; ++i)
#pragma unroll
      for (int j = 0; j < 4; ++j) acc[i][j] = 0.f;
    for (int s = 0; s < 8; ++s) {
      const int kk0 = s * 32;
      __syncthreads();
#pragma unroll
      for (int j = 0; j < 4; ++j) {
        const int slot = wid + 4 * j;
        const int m = slot >> 1, half = slot & 1;
        gl_lds16((half ? aptrH : aptrL) + kk0 + 4 * m, &As4[m * 128 + half * 64]);
      }
#pragma unroll
      for (int j = 0; j < 2; ++j) {
        const int m = wid + 4 * j;
        gl_lds16(bptr + kk0 + 4 * m, &Bs4[m * 64]);
      }
      __syncthreads();
#pragma unroll
      for (int k4 = 0; k4 < 8; ++k4) {
        float4 a[8], b[4];
#pragma unroll
        for (int i = 0; i < 8; ++i) a[i] = As4[k4 * 128 + ty + 16 * i];
#pragma unroll
        for (int j = 0; j < 4; ++j) b[j] = Bs4[k4 * 64 + tx + 16 * j];
#pragma unroll
        for (int i = 0; i < 8; ++i)
#pragma unroll
          for (int j = 0; j < 4; ++j) { DOT4(acc[i][j], a[i], b[j]) }
      }
    }
#pragma unroll
    for (int i = 0; i < 8; ++i) {
      const int r = row0 + ty + 16 * i;
#pragma unroll
      for (int j = 0; j < 4; ++j) {
        const int c = col0 + tx + 16 * j;
        if (acc[i][j] > tau_r[i] && c < N && r < B) {
          int p = atomicAdd(&cnt[r], 1);
          if (p < CAP) cidx[(size_t)r * CAP + p] = c;
        }
      }
    }
  }
}

// ------------------------------------------------- fallback full rescan
__global__ void k_fallback(const float* __restrict__ train, const float* __restrict__ qs,
                           int* __restrict__ cidx, int* __restrict__ cnt, int N) {
  const int row = blockIdx.x;
  const int t = threadIdx.x;
  const int c0 = cnt[row];
  if (c0 >= 10 && c0 <= CAP) return;
  __shared__ float q[DDIM];
  if (t < DDIM) q[t] = qs[(size_t)row * DDIM + t];
  __syncthreads();
  float lv[10]; int li[10];
#pragma unroll
  for (int k = 0; k < 10; ++k) { lv[k] = -INFINITY; li[k] = 0x7FFFFFFF; }
  for (int c = t; c < N; c += 256) {
    const float* tr = train + (size_t)c * DDIM;
    float s = 0.f;
    for (int d = 0; d < DDIM; ++d) s = fmaf(q[d], tr[d], s);
    if (s > lv[9]) {
      int p = 9;
      while (p > 0 && s > lv[p - 1]) { lv[p] = lv[p - 1]; li[p] = li[p - 1]; --p; }
      lv[p] = s; li[p] = c;
    }
  }
  __shared__ float rv[256]; __shared__ int ri[256]; __shared__ int rt_[256];
  __shared__ int topi[10];
  int pt = 0;
  for (int k = 0; k < 10; ++k) {
    rv[t] = (pt < 10) ? lv[pt] : -INFINITY;
    ri[t] = (pt < 10) ? li[pt] : 0x7FFFFFFF;
    rt_[t] = t;
    __syncthreads();
    for (int s2 = 128; s2 > 0; s2 >>= 1) {
      if (t < s2) {
        float ov = rv[t + s2]; int oi = ri[t + s2];
        if (ov > rv[t] || (ov == rv[t] && oi < ri[t])) {
          rv[t] = ov; ri[t] = oi; rt_[t] = rt_[t + s2];
        }
      }
      __syncthreads();
    }
    const int win = rt_[0];
    if (t == 0) topi[k] = ri[0];
    __syncthreads();
    if (t == win) ++pt;
  }
  if (t < 10) cidx[(size_t)row * CAP + t] = topi[t];
  if (t == 0) cnt[row] = 10;
}

// ------------------------------------------------- fp64 rescore
__global__ void k_rescore(const float* __restrict__ train, const float* __restrict__ qs,
                          const int* __restrict__ cidx, const int* __restrict__ cnt,
                          double* __restrict__ dval) {
  const int row = blockIdx.x;
  const int t = threadIdx.x, wid = t >> 6, lane = t & 63;
  __shared__ float qsh[DDIM];
  if (t < DDIM) qsh[t] = qs[(size_t)row * DDIM + t];
  __syncthreads();
  int n = cnt[row]; if (n > CAP) n = CAP;
  for (int ci = wid; ci < n; ci += 4) {
    const int c = cidx[(size_t)row * CAP + ci];
    const float4 tv = *(const float4*)(train + (size_t)c * DDIM + lane * 4);
    const float4 qv = *(const float4*)(qsh + lane * 4);
    double s = (double)tv.x * qv.x + (double)tv.y * qv.y +
               (double)tv.z * qv.z + (double)tv.w * qv.w;
#pragma unroll
    for (int o = 32; o > 0; o >>= 1) s += __shfl_down(s, o, 64);
    if (lane == 0) dval[(size_t)row * CAP + ci] = s;
  }
}

// ------------------------------------------------- finalize
__global__ void k_finalize(const double* __restrict__ dval, const int* __restrict__ cidx,
                           const int* __restrict__ cnt, const int* __restrict__ labels,
                           float* __restrict__ out) {
  const int row = blockIdx.x;
  const int t = threadIdx.x;
  int n = cnt[row]; if (n > CAP) n = CAP;
  __shared__ double sv[CAP]; __shared__ int si[CAP];
  for (int i = t; i < CAP; i += 256) {
    sv[i] = (i < n) ? dval[(size_t)row * CAP + i] : -INFINITY;
    si[i] = (i < n) ? cidx[(size_t)row * CAP + i] : 0x7FFFFFFF;
  }
  __syncthreads();
  __shared__ double rv[256]; __shared__ int ri[256]; __shared__ int rp[256];
  __shared__ double topv[10]; __shared__ int topl[10];
  __shared__ int wpos;
  for (int k = 0; k < 10; ++k) {
    double bv = sv[t]; int bi = si[t]; int bp = t;
    if (t + 256 < CAP) {
      double v2 = sv[t + 256]; int i2 = si[t + 256];
      if (v2 > bv || (v2 == bv && i2 < bi)) { bv = v2; bi = i2; bp = t + 256; }
    }
    rv[t] = bv; ri[t] = bi; rp[t] = bp;
    __syncthreads();
    for (int s2 = 128; s2 > 0; s2 >>= 1) {
      if (t < s2) {
        double ov = rv[t + s2]; int oi = ri[t + s2];
        if (ov > rv[t] || (ov == rv[t] && oi < ri[t])) {
          rv[t] = ov; ri[t] = oi; rp[t] = rp[t + s2];
        }
      }
      __syncthreads();
    }
    if (t == 0) { topv[k] = rv[0]; topl[k] = ri[0]; wpos = rp[0]; }
    __syncthreads();
    if (t == 0) sv[wpos] = -INFINITY;
    __syncthreads();
  }
  __shared__ double oc[NCLS];
  if (t < NCLS) oc[t] = 0.0;
  __syncthreads();
  if (t == 0) {
    const double m = topv[0];
    double w[10]; double ssum = 0.0;
#pragma unroll
    for (int k = 0; k < 10; ++k) { w[k] = exp((topv[k] - m) / 0.07); ssum += w[k]; }
#pragma unroll
    for (int k = 0; k < 10; ++k) oc[labels[topl[k]]] += w[k] / ssum;
  }
  __syncthreads();
  if (t < NCLS) out[(size_t)row * NCLS + t] = (float)oc[t];
}

// ------------------------------------------------- launch
extern "C" void kernel_launch(void* const* d_in, const int* in_sizes, int n_in,
                              void* d_out, int out_size, void* d_ws, size_t ws_size,
                              hipStream_t stream) {
  const float* test   = (const float*)d_in[0];
  const float* train  = (const float*)d_in[1];
  const int*   labels = (const int*)d_in[2];
  float* out = (float*)d_out;
  const int B = in_sizes[0] / DDIM;   // 1024
  const int N = in_sizes[2];          // 200000
  (void)n_in; (void)out_size;

  char* w = (char*)d_ws;
  size_t off = 0;
  auto alloc = [&](size_t bytes) {
    size_t o = off; off = (off + bytes + 255) & ~(size_t)255; return o;
  };
  double* colsq = (double*)(w + alloc(2048));
  int*    cnt   = (int*)(w + alloc((size_t)B * 4));
  float*  tau   = (float*)(w + alloc((size_t)B * 4));
  float*  qs    = (float*)(w + alloc((size_t)B * DDIM * 4));
  __hip_bfloat16* qs_bf = (__hip_bfloat16*)(w + alloc((size_t)B * DDIM * 2));
  int*    cidx  = (int*)(w + alloc((size_t)B * CAP * 4));
  double* dval  = (double*)(w + alloc((size_t)B * CAP * 8));
  __hip_bfloat16* train_bf = (__hip_bfloat16*)(w + alloc((size_t)N * DDIM * 2));
  const bool use_mfma = (ws_size >= off);

  hipMemsetAsync(d_ws, 0, 2048 + (size_t)B * 4, stream);   // colsq + cnt

  if (use_mfma) {
    hipLaunchKernelGGL(k_cast_colsq, dim3(1024), dim3(256), 0, stream,
                       train, train_bf, colsq, N);
    hipLaunchKernelGGL(k_prep, dim3(B), dim3(256), 0, stream,
                       test, colsq, qs, qs_bf, tau, B);
    hipLaunchKernelGGL(k_mfma, dim3((N + 127) / 128, (B + 127) / 128),
                       dim3(256), 0, stream, qs_bf, train_bf, tau, cidx, cnt, N, B);
  } else {
    hipLaunchKernelGGL(k_cast_colsq, dim3(1024), dim3(256), 0, stream,
                       train, (__hip_bfloat16*)nullptr, colsq, N);
    hipLaunchKernelGGL(k_prep, dim3(B), dim3(256), 0, stream,
                       test, colsq, qs, qs_bf, tau, B);
    const int CT = (N + 63) / 64;
    const int rb = (B + 127) / 128;
    int bx = 2048 / (rb > 0 ? rb : 1); if (bx < 1) bx = 1;
    int tpc = (CT + bx - 1) / bx;
    int chunks = (CT + tpc - 1) / tpc;
    hipLaunchKernelGGL(k_gemm, dim3(chunks, rb), dim3(256), 0, stream,
                       train, qs, tau, cidx, cnt, N, B, tpc);
  }

  hipLaunchKernelGGL(k_fallback, dim3(B), dim3(256), 0, stream,
                     train, qs, cidx, cnt, N);
  hipLaunchKernelGGL(k_rescore,  dim3(B), dim3(256), 0, stream,
                     train, qs, cidx, cnt, dval);
  hipLaunchKernelGGL(k_finalize, dim3(B), dim3(256), 0, stream,
                     dval, cidx, cnt, labels, out);
}